// Round 2
// baseline (592.838 us; speedup 1.0000x reference)
//
#include <hip/hip_runtime.h>
#include <hip/hip_bf16.h>
#include <cstdint>

#define S_LEN 2304
#define NDIM  3072
#define NH    24
#define HD    128

typedef unsigned short u16;
typedef __bf16  bf16x8  __attribute__((ext_vector_type(8)));
typedef float   floatx4 __attribute__((ext_vector_type(4)));

__device__ __forceinline__ u16 f2bf(float x) {
  union { float f; unsigned int u; } a; a.f = x;
  unsigned int r = (a.u + 0x7FFFu + ((a.u >> 16) & 1u)) >> 16;
  return (u16)r;
}

// async 16B global->LDS (direct-to-shared DMA). LDS dest must be
// wave-uniform base + lane*16 -- all call sites arrange that.
__device__ __forceinline__ void async_load16(const void* g, void* l) {
  auto gp = (const __attribute__((address_space(1))) unsigned int*)(unsigned long long)(g);
  auto lp = (__attribute__((address_space(3))) unsigned int*)(unsigned int)(unsigned long long)(l);
  __builtin_amdgcn_global_load_lds(gp, lp, 16, 0, 0);
}

// ------------------------------------------- fp32->bf16, all 5 tensors fused
__global__ __launch_bounds__(256) void cvt_all(const float* __restrict__ x,
                                               const float* __restrict__ w0,
                                               const float* __restrict__ w1,
                                               const float* __restrict__ w2,
                                               const float* __restrict__ w3,
                                               u16* __restrict__ xo,
                                               u16* __restrict__ o0,
                                               u16* __restrict__ o1,
                                               u16* __restrict__ o2,
                                               u16* __restrict__ o3) {
  long b = blockIdx.x;
  const float* in; u16* out;
  if (b < 3456) { in = x; out = xo; }
  else {
    long wi = (b - 3456) / 4608;
    b = (b - 3456) % 4608;
    in  = (wi == 0) ? w0 : (wi == 1) ? w1 : (wi == 2) ? w2 : w3;
    out = (wi == 0) ? o0 : (wi == 1) ? o1 : (wi == 2) ? o2 : o3;
  }
  long i = (b * 256 + threadIdx.x) * 8;
  float4 a = *(const float4*)(in + i);
  float4 c = *(const float4*)(in + i + 4);
  union { u16 h[8]; uint4 u; } r;
  r.h[0] = f2bf(a.x); r.h[1] = f2bf(a.y); r.h[2] = f2bf(a.z); r.h[3] = f2bf(a.w);
  r.h[4] = f2bf(c.x); r.h[5] = f2bf(c.y); r.h[6] = f2bf(c.z); r.h[7] = f2bf(c.w);
  *(uint4*)(out + i) = r.u;
}

// ---------------------------------------------------------------- GEMM core
// C[M,N] = A[M,K] @ B[N,K]^T.  A,B bf16; acc fp32.
// PROVEN structure (887 TF measured on this problem): 128x128 tile, BK=64,
// 256 threads = 4 waves of 64x64, single-buffered LDS (32 KB -> ~2.25
// blocks/CU resident; cross-block overlap hides the barrier drain).
__device__ __forceinline__ void gemm_core128(const u16* __restrict__ A,
                                             const u16* __restrict__ B,
                                             int bm, int bn,
                                             u16* As, u16* Bs,
                                             floatx4 acc[4][4]) {
  constexpr int K = NDIM;
  const int t = threadIdx.x;
  const int l = t & 63, w = t >> 6;
  const int l15 = l & 15, quad = l >> 4;
  const int wm = (w >> 1) * 64, wn = (w & 1) * 64;

#pragma unroll
  for (int i = 0; i < 4; ++i)
#pragma unroll
    for (int j = 0; j < 4; ++j) acc[i][j] = {0.f, 0.f, 0.f, 0.f};

  for (int kt = 0; kt < K / 64; ++kt) {
    const int k0 = kt * 64;
#pragma unroll
    for (int i = 0; i < 4; ++i) {
      int p = i * 256 + t;            // chunk index 0..1023 (wave-contiguous)
      int r = p >> 3;
      int c = (p & 7) ^ (r & 7);      // fetch the chunk that lands swizzled
      async_load16(A + (long)(bm + r) * K + k0 + c * 8, As + p * 8);
      async_load16(B + (long)(bn + r) * K + k0 + c * 8, Bs + p * 8);
    }
    __syncthreads();
#pragma unroll
    for (int kk = 0; kk < 2; ++kk) {
      bf16x8 af[4], bfr[4];
#pragma unroll
      for (int i = 0; i < 4; ++i) {
        int row = wm + i * 16 + l15;
        int cc = kk * 4 + quad;
        af[i] = *(const bf16x8*)(As + (row * 8 + (cc ^ (row & 7))) * 8);
      }
#pragma unroll
      for (int j = 0; j < 4; ++j) {
        int row = wn + j * 16 + l15;
        int cc = kk * 4 + quad;
        bfr[j] = *(const bf16x8*)(Bs + (row * 8 + (cc ^ (row & 7))) * 8);
      }
#pragma unroll
      for (int i = 0; i < 4; ++i)
#pragma unroll
        for (int j = 0; j < 4; ++j)
          acc[i][j] = __builtin_amdgcn_mfma_f32_16x16x32_bf16(af[i], bfr[j], acc[i][j], 0, 0, 0);
    }
    __syncthreads();
  }
}

// fused Q,K,V projection. 1296 blocks, XCD-chunked swizzle: each XCD gets a
// contiguous run of 162 tiles along M-rows -> concurrent A working set per
// XCD is 1-2 panels (<=1.5 MB, L2-resident) instead of 9 (6.75 MB, LLC).
// q,k -> fp32 (RMSNorm wants fp32); v -> bf16 directly.
__global__ __launch_bounds__(256, 2) void gemm_qkv(const u16* __restrict__ A,
                                                   const u16* __restrict__ wq,
                                                   const u16* __restrict__ wk,
                                                   const u16* __restrict__ wv,
                                                   const float* __restrict__ bq,
                                                   const float* __restrict__ bk,
                                                   const float* __restrict__ bv,
                                                   float* __restrict__ qf,
                                                   float* __restrict__ kf,
                                                   u16* __restrict__ vbf) {
  __shared__ u16 As[128 * 64];
  __shared__ u16 Bs[128 * 64];
  const int bid = blockIdx.x;                 // 0..1295 = 8 * 162
  const int swz = (bid & 7) * 162 + (bid >> 3);
  const int tm = swz / 72;                    // 0..17
  const int tn = swz % 72;                    // 0..71
  const int sel = tn / 24;                    // 0:q 1:k 2:v
  const int bn = (tn % 24) * 128;
  const int bm = tm * 128;
  const u16* Bw = (sel == 0) ? wq : (sel == 1) ? wk : wv;
  const float* bias = (sel == 0) ? bq : (sel == 1) ? bk : bv;

  floatx4 acc[4][4];
  gemm_core128(A, Bw, bm, bn, As, Bs, acc);

  const int t = threadIdx.x;
  const int l = t & 63, w = t >> 6;
  const int l15 = l & 15, quad = l >> 4;
  const int wm = (w >> 1) * 64, wn = (w & 1) * 64;

  if (sel < 2) {
    float* C = sel ? kf : qf;
#pragma unroll
    for (int i = 0; i < 4; ++i) {
      const int gm = bm + wm + i * 16 + quad * 4;
#pragma unroll
      for (int j = 0; j < 4; ++j) {
        const int gn = bn + wn + j * 16 + l15;
        const float bb = bias[gn];
#pragma unroll
        for (int r = 0; r < 4; ++r)
          C[(long)(gm + r) * NDIM + gn] = acc[i][j][r] + bb;
      }
    }
  } else {
#pragma unroll
    for (int i = 0; i < 4; ++i) {
      const int gm = bm + wm + i * 16 + quad * 4;
#pragma unroll
      for (int j = 0; j < 4; ++j) {
        const int gn = bn + wn + j * 16 + l15;
        const float bb = bias[gn];
#pragma unroll
        for (int r = 0; r < 4; ++r)
          vbf[(long)(gm + r) * NDIM + gn] = f2bf(acc[i][j][r] + bb);
      }
    }
  }
}

// output projection: 432 blocks (18 M x 24 N), XCD-chunked (432 = 8 * 54).
__global__ __launch_bounds__(256, 2) void gemm_bt(const u16* __restrict__ A,
                                                  const u16* __restrict__ Bw,
                                                  const float* __restrict__ bias,
                                                  float* __restrict__ C) {
  __shared__ u16 As[128 * 64];
  __shared__ u16 Bs[128 * 64];
  const int bid = blockIdx.x;
  const int swz = (bid & 7) * 54 + (bid >> 3);
  const int tm = swz / 24;
  const int tn = swz % 24;
  const int bm = tm * 128;
  const int bn = tn * 128;

  floatx4 acc[4][4];
  gemm_core128(A, Bw, bm, bn, As, Bs, acc);

  const int t = threadIdx.x;
  const int l = t & 63, w = t >> 6;
  const int l15 = l & 15, quad = l >> 4;
  const int wm = (w >> 1) * 64, wn = (w & 1) * 64;
#pragma unroll
  for (int i = 0; i < 4; ++i) {
    const int gm = bm + wm + i * 16 + quad * 4;
#pragma unroll
    for (int j = 0; j < 4; ++j) {
      const int gn = bn + wn + j * 16 + l15;
      const float bb = bias[gn];
#pragma unroll
      for (int r = 0; r < 4; ++r)
        C[(long)(gm + r) * NDIM + gn] = acc[i][j][r] + bb;
    }
  }
}

// --------------------------------------------------- fused RMSNorm + 3D RoPE
// blockIdx.y: 0 -> q, 1 -> k
__global__ __launch_bounds__(256) void rmsnorm_rope(const float* __restrict__ qxf,
                                                    const float* __restrict__ kxf,
                                                    const float* __restrict__ gqp,
                                                    const float* __restrict__ gkp,
                                                    const float* __restrict__ freqs,
                                                    const int* __restrict__ gsz,
                                                    u16* __restrict__ qop,
                                                    u16* __restrict__ kop) {
  const int tok = blockIdx.x;
  const int tid = threadIdx.x;
  const float* xf = blockIdx.y ? kxf : qxf;
  const float* g  = blockIdx.y ? gkp : gqp;
  u16* outp       = blockIdx.y ? kop : qop;
  const float* row = xf + (long)tok * NDIM;
  float4 v[3];
  float ss = 0.f;
#pragma unroll
  for (int p = 0; p < 3; ++p) {
    v[p] = ((const float4*)row)[p * 256 + tid];
    ss += v[p].x * v[p].x + v[p].y * v[p].y + v[p].z * v[p].z + v[p].w * v[p].w;
  }
#pragma unroll
  for (int m = 1; m < 64; m <<= 1) ss += __shfl_xor(ss, m);
  __shared__ float red[4];
  if ((tid & 63) == 0) red[tid >> 6] = ss;
  __syncthreads();
  ss = red[0] + red[1] + red[2] + red[3];
  const float scale = rsqrtf(ss * (1.0f / NDIM) + 1e-6f);

  const int gh = gsz[1], gw = gsz[2];
  const int hw = gh * gw;
  const int fi = tok / hw;
  const int hi = (tok % hw) / gw;
  const int wi = tok % gw;
#pragma unroll
  for (int p = 0; p < 3; ++p) {
    const int e0 = (p * 256 + tid) * 4;
    const float4 gg = ((const float4*)g)[p * 256 + tid];
    const int hh = e0 >> 7;
    const int d = e0 & 127;
    const int c0 = d >> 1;
    int pos0 = (c0 < 22) ? fi : ((c0 < 43) ? hi : wi);
    int pos1 = (c0 + 1 < 22) ? fi : ((c0 + 1 < 43) ? hi : wi);
    float th0 = freqs[pos0 * 64 + c0];
    float th1 = freqs[pos1 * 64 + c0 + 1];
    float s0, cc0, s1, cc1;
    __sincosf(th0, &s0, &cc0);
    __sincosf(th1, &s1, &cc1);
    float x0 = v[p].x * scale * gg.x;
    float x1 = v[p].y * scale * gg.y;
    float x2 = v[p].z * scale * gg.z;
    float x3 = v[p].w * scale * gg.w;
    union { u16 h[4]; uint2 u; } o;
    o.h[0] = f2bf(x0 * cc0 - x1 * s0);
    o.h[1] = f2bf(x0 * s0 + x1 * cc0);
    o.h[2] = f2bf(x2 * cc1 - x3 * s1);
    o.h[3] = f2bf(x2 * s1 + x3 * cc1);
    *(uint2*)(outp + ((long)hh * S_LEN + tok) * HD + d) = o.u;
  }
}

// ----------------------------------------------- V: [S,3072] bf16 -> [3072,S] bf16
__global__ __launch_bounds__(256) void vtrans(const u16* __restrict__ vb,
                                              u16* __restrict__ vt) {
  __shared__ u16 tile[64][66];
  const int c0 = blockIdx.x * 64;
  const int t0 = blockIdx.y * 64;
  const int tid = threadIdx.x;
#pragma unroll
  for (int it = 0; it < 16; ++it) {
    int idx = it * 256 + tid;
    int r = idx >> 6, c = idx & 63;
    tile[r][c] = vb[(long)(t0 + r) * NDIM + c0 + c];
  }
  __syncthreads();
#pragma unroll
  for (int it = 0; it < 16; ++it) {
    int idx = it * 256 + tid;
    int r = idx >> 6, c = idx & 63;
    vt[(long)(c0 + r) * S_LEN + t0 + c] = tile[c][r];
  }
}

// ------------------------------------------------------------ flash attention
// qb,kb: bf16 [NH][S][HD]; vt: bf16 [NH*HD][S]; out: bf16 [S][3072].
// 432 blocks x 256 threads (4 waves x 32 q-rows, Q-tile 128). K-tile = 64,
// double-buffered (prefetch issued right after the single per-iter barrier).
// NO online max: post-RMSNorm |s*SC| <= ~11 so exp is fp32-safe un-shifted;
// row-sum l comes from an MFMA with an all-ones B operand. LDS = 80 KB ->
// 2 blocks/CU. XCD swizzle: b&7 -> xcd, 3 heads x 18 qtiles per XCD.
__global__ __launch_bounds__(256, 2) void attn_kern(const u16* __restrict__ qb,
                                                    const u16* __restrict__ kb,
                                                    const u16* __restrict__ vt,
                                                    const int* __restrict__ seq_lens,
                                                    u16* __restrict__ ob) {
  __shared__ u16 Kb[2][64 * 128];   // K tile: 64 tok rows x 16 chunks, swz 15
  __shared__ u16 Vb[2][128 * 64];   // V^T tile: 128 d rows x 8 chunks, swz 7
  __shared__ u16 Ps[128 * 64];      // P tile: 128 q rows x 8 chunks, swz 7
  const int b = blockIdx.x;           // 0..431
  const int xcd = b & 7;
  const int slot = b >> 3;            // 0..53
  const int h = xcd * 3 + slot / 18;  // 3 heads per XCD
  const int qt = slot % 18;
  const int t = threadIdx.x;
  const int l = t & 63, w = t >> 6;
  const int l15 = l & 15, quad = l >> 4;
  const int seqlen = seq_lens[0];
  const float SC2 = 0.12753102543f;   // (1/sqrt(128)) * log2(e), for exp2f

  const u16* kbase = kb + (long)h * S_LEN * HD;
  const u16* vbase = vt + (long)h * HD * S_LEN;

  // Q fragments: A-layout m = lane&15, k = quad*8 + j
  bf16x8 qfrag[2][4];
#pragma unroll
  for (int i = 0; i < 2; ++i) {
    const u16* qrow = qb + ((long)h * S_LEN + qt * 128 + w * 32 + i * 16 + l15) * HD + quad * 8;
#pragma unroll
    for (int kk = 0; kk < 4; ++kk) qfrag[i][kk] = *(const bf16x8*)(qrow + kk * 32);
  }

  bf16x8 ones;
#pragma unroll
  for (int i = 0; i < 8; ++i) ones[i] = (__bf16)1.0f;

  floatx4 oacc[2][8];
  floatx4 lacc[2];
#pragma unroll
  for (int i = 0; i < 2; ++i) {
#pragma unroll
    for (int j = 0; j < 8; ++j) oacc[i][j] = {0.f, 0.f, 0.f, 0.f};
    lacc[i] = {0.f, 0.f, 0.f, 0.f};
  }

  // stage K-tile (64x128) + V-tile (128x64) for tile `kt` into buffer `buf`
  auto stage = [&](int kt, int buf) {
#pragma unroll
    for (int i = 0; i < 4; ++i) {
      int p = i * 256 + t;              // 0..1023
      int rk = p >> 4;                  // K: token row 0..63
      int ck = (p & 15) ^ (rk & 15);
      async_load16(kbase + ((long)(kt * 64 + rk)) * HD + ck * 8, &Kb[buf][p * 8]);
      int dv = p >> 3;                  // V: hd row 0..127
      int cv = (p & 7) ^ (dv & 7);
      async_load16(vbase + (long)dv * S_LEN + kt * 64 + cv * 8, &Vb[buf][p * 8]);
    }
  };

  stage(0, 0);

  for (int kt = 0; kt < S_LEN / 64; ++kt) {
    const int cur = kt & 1;
    __syncthreads();                   // tile kt loads done; prev compute done
    if (kt + 1 < S_LEN / 64) stage(kt + 1, cur ^ 1);

    // S = Q K^T  (128q x 64k)
    floatx4 sacc[2][4];
#pragma unroll
    for (int i = 0; i < 2; ++i)
#pragma unroll
      for (int j = 0; j < 4; ++j) sacc[i][j] = {0.f, 0.f, 0.f, 0.f};
#pragma unroll
    for (int kk = 0; kk < 4; ++kk) {
#pragma unroll
      for (int j = 0; j < 4; ++j) {
        int row = j * 16 + l15;
        int cc = kk * 4 + quad;
        bf16x8 bk = *(const bf16x8*)(&Kb[cur][(row * 16 + (cc ^ (row & 15))) * 8]);
        sacc[0][j] = __builtin_amdgcn_mfma_f32_16x16x32_bf16(qfrag[0][kk], bk, sacc[0][j], 0, 0, 0);
        sacc[1][j] = __builtin_amdgcn_mfma_f32_16x16x32_bf16(qfrag[1][kk], bk, sacc[1][j], 0, 0, 0);
      }
    }

    // unshifted softmax numerator: p = 2^(s*SC2)  (masked cols -> 0)
    const bool tail = (kt * 64 + 64 > seqlen);
#pragma unroll
    for (int i = 0; i < 2; ++i)
#pragma unroll
      for (int j = 0; j < 4; ++j)
#pragma unroll
        for (int r = 0; r < 4; ++r) {
          float sv = sacc[i][j][r] * SC2;
          if (tail) {
            int col = kt * 64 + j * 16 + l15;
            if (col >= seqlen) sv = -1e30f;
          }
          sacc[i][j][r] = exp2f(sv);
        }

    // write P into its own buffer (wave-private rows -> no barrier)
#pragma unroll
    for (int i = 0; i < 2; ++i)
#pragma unroll
      for (int j = 0; j < 4; ++j)
#pragma unroll
        for (int r = 0; r < 4; ++r) {
          int rq = w * 32 + i * 16 + quad * 4 + r;   // 0..127
          int ct = j * 16 + l15;                     // 0..63
          int cc = ct >> 3;
          Ps[(rq * 8 + (cc ^ (rq & 7))) * 8 + (ct & 7)] = f2bf(sacc[i][j][r]);
        }

    // O += P V ; l += P @ ones  (A-frags: own rows of Ps)
#pragma unroll
    for (int kl = 0; kl < 2; ++kl) {
      bf16x8 ap[2];
#pragma unroll
      for (int i = 0; i < 2; ++i) {
        int row = w * 32 + i * 16 + l15;
        int cc = kl * 4 + quad;
        ap[i] = *(const bf16x8*)(&Ps[(row * 8 + (cc ^ (row & 7))) * 8]);
      }
      lacc[0] = __builtin_amdgcn_mfma_f32_16x16x32_bf16(ap[0], ones, lacc[0], 0, 0, 0);
      lacc[1] = __builtin_amdgcn_mfma_f32_16x16x32_bf16(ap[1], ones, lacc[1], 0, 0, 0);
#pragma unroll
      for (int j = 0; j < 8; ++j) {
        int d = j * 16 + l15;
        int ccv = kl * 4 + quad;
        bf16x8 bv = *(const bf16x8*)(&Vb[cur][(d * 8 + (ccv ^ (d & 7))) * 8]);
        oacc[0][j] = __builtin_amdgcn_mfma_f32_16x16x32_bf16(ap[0], bv, oacc[0][j], 0, 0, 0);
        oacc[1][j] = __builtin_amdgcn_mfma_f32_16x16x32_bf16(ap[1], bv, oacc[1][j], 0, 0, 0);
      }
    }
  }

  // epilogue: out[t][h*128+d] = O / l
#pragma unroll
  for (int i = 0; i < 2; ++i) {
    float inv[4];
#pragma unroll
    for (int r = 0; r < 4; ++r) inv[r] = 1.0f / lacc[i][r];
#pragma unroll
    for (int j = 0; j < 8; ++j) {
      int gt = qt * 128 + w * 32 + i * 16 + quad * 4;
      int gc = h * HD + j * 16 + l15;
#pragma unroll
      for (int r = 0; r < 4; ++r)
        ob[(long)(gt + r) * NDIM + gc] = f2bf(oacc[i][j][r] * inv[r]);
    }
  }
}

// ----------------------------------------------------------------------------
extern "C" void kernel_launch(void* const* d_in, const int* in_sizes, int n_in,
                              void* d_out, int out_size, void* d_ws, size_t ws_size,
                              hipStream_t stream) {
  const float* x        = (const float*)d_in[0];
  const int*   seq_lens = (const int*)  d_in[1];
  const int*   gsz      = (const int*)  d_in[2];
  const float* freqs    = (const float*)d_in[3];
  const float* wq       = (const float*)d_in[4];
  const float* bq       = (const float*)d_in[5];
  const float* wk       = (const float*)d_in[6];
  const float* bk       = (const float*)d_in[7];
  const float* wv       = (const float*)d_in[8];
  const float* bv       = (const float*)d_in[9];
  const float* wo       = (const float*)d_in[10];
  const float* bo       = (const float*)d_in[11];
  const float* gq       = (const float*)d_in[12];
  const float* gk       = (const float*)d_in[13];
  float* out = (float*)d_out;

  char* ws = (char*)d_ws;
  const size_t SD2 = (size_t)S_LEN * NDIM * 2;   // bf16 [S,3072]
  const size_t W2  = (size_t)NDIM * NDIM * 2;    // bf16 [3072,3072]
  const size_t SD4 = (size_t)S_LEN * NDIM * 4;   // fp32 [S,3072]
  size_t off = 0;
  u16* xb    = (u16*)(ws + off); off += SD2;
  u16* wqb   = (u16*)(ws + off); off += W2;
  u16* wkb   = (u16*)(ws + off); off += W2;
  u16* wvb   = (u16*)(ws + off); off += W2;
  u16* wob   = (u16*)(ws + off); off += W2;
  float* qf  = (float*)(ws + off); off += SD4;
  float* kf  = (float*)(ws + off); off += SD4;
  u16* vbf   = (u16*)(ws + off); off += SD4;    // fp32-sized slot; holds bf16
  u16* qbuf  = (u16*)(ws + off); off += SD2;
  u16* kbuf  = (u16*)(ws + off); off += SD2;
  u16* vtb   = (u16*)(ws + off); off += SD2;
  u16* attnb = (u16*)(ws + off); off += SD2;

  cvt_all<<<3456 + 4 * 4608, 256, 0, stream>>>(x, wq, wk, wv, wo,
                                               xb, wqb, wkb, wvb, wob);

  gemm_qkv<<<1296, 256, 0, stream>>>(xb, wqb, wkb, wvb,
                                     bq, bk, bv, qf, kf, vbf);

  rmsnorm_rope<<<dim3(S_LEN, 2), 256, 0, stream>>>(qf, kf, gq, gk, freqs, gsz,
                                                   qbuf, kbuf);
  vtrans<<<dim3(NDIM / 64, S_LEN / 64), 256, 0, stream>>>(vbf, vtb);

  attn_kern<<<432, 256, 0, stream>>>(qbuf, kbuf, vtb, seq_lens, attnb);

  gemm_bt<<<432, 256, 0, stream>>>(attnb, wob, bo, out);
}

// Round 3
// 552.052 us; speedup vs baseline: 1.0739x; 1.0739x over previous
//
#include <hip/hip_runtime.h>
#include <hip/hip_bf16.h>
#include <cstdint>

#define S_LEN 2304
#define NDIM  3072
#define NH    24
#define HD    128

typedef unsigned short u16;
typedef __bf16  bf16x8  __attribute__((ext_vector_type(8)));
typedef float   floatx4 __attribute__((ext_vector_type(4)));

__device__ __forceinline__ u16 f2bf(float x) {
  union { float f; unsigned int u; } a; a.f = x;
  unsigned int r = (a.u + 0x7FFFu + ((a.u >> 16) & 1u)) >> 16;
  return (u16)r;
}

// async 16B global->LDS (direct-to-shared DMA). LDS dest must be
// wave-uniform base + lane*16 -- all call sites arrange that.
__device__ __forceinline__ void async_load16(const void* g, void* l) {
  auto gp = (const __attribute__((address_space(1))) unsigned int*)(unsigned long long)(g);
  auto lp = (__attribute__((address_space(3))) unsigned int*)(unsigned int)(unsigned long long)(l);
  __builtin_amdgcn_global_load_lds(gp, lp, 16, 0, 0);
}

// ------------------------------------------- fp32->bf16, all 5 tensors fused
__global__ __launch_bounds__(256) void cvt_all(const float* __restrict__ x,
                                               const float* __restrict__ w0,
                                               const float* __restrict__ w1,
                                               const float* __restrict__ w2,
                                               const float* __restrict__ w3,
                                               u16* __restrict__ xo,
                                               u16* __restrict__ o0,
                                               u16* __restrict__ o1,
                                               u16* __restrict__ o2,
                                               u16* __restrict__ o3) {
  long b = blockIdx.x;
  const float* in; u16* out;
  if (b < 3456) { in = x; out = xo; }
  else {
    long wi = (b - 3456) / 4608;
    b = (b - 3456) % 4608;
    in  = (wi == 0) ? w0 : (wi == 1) ? w1 : (wi == 2) ? w2 : w3;
    out = (wi == 0) ? o0 : (wi == 1) ? o1 : (wi == 2) ? o2 : o3;
  }
  long i = (b * 256 + threadIdx.x) * 8;
  float4 a = *(const float4*)(in + i);
  float4 c = *(const float4*)(in + i + 4);
  union { u16 h[8]; uint4 u; } r;
  r.h[0] = f2bf(a.x); r.h[1] = f2bf(a.y); r.h[2] = f2bf(a.z); r.h[3] = f2bf(a.w);
  r.h[4] = f2bf(c.x); r.h[5] = f2bf(c.y); r.h[6] = f2bf(c.z); r.h[7] = f2bf(c.w);
  *(uint4*)(out + i) = r.u;
}

// ---------------------------------------------------------------- GEMM core
// C[M,N] = A[M,K] @ B[N,K]^T.  A,B bf16; acc fp32.
// PROVEN structure (887 TF / 147us qkv measured on this problem): 128x128
// tile, BK=64, 256 threads = 4 waves of 64x64, single-buffered LDS (32 KB ->
// ~2 blocks/CU; cross-block wave overlap hides the barrier drain).
// Grid mapping: PLAIN x-fastest over N-tiles (NO XCD chunking -- measured
// 161MB fetch vs 503MB chunked: device-wide temporally-correlated sweep is
// what keeps B panels L2/LLC-resident here).
__device__ __forceinline__ void gemm_core128(const u16* __restrict__ A,
                                             const u16* __restrict__ B,
                                             int bm, int bn,
                                             u16* As, u16* Bs,
                                             floatx4 acc[4][4]) {
  constexpr int K = NDIM;
  const int t = threadIdx.x;
  const int l = t & 63, w = t >> 6;
  const int l15 = l & 15, quad = l >> 4;
  const int wm = (w >> 1) * 64, wn = (w & 1) * 64;

#pragma unroll
  for (int i = 0; i < 4; ++i)
#pragma unroll
    for (int j = 0; j < 4; ++j) acc[i][j] = {0.f, 0.f, 0.f, 0.f};

  for (int kt = 0; kt < K / 64; ++kt) {
    const int k0 = kt * 64;
#pragma unroll
    for (int i = 0; i < 4; ++i) {
      int p = i * 256 + t;            // chunk index 0..1023 (wave-contiguous)
      int r = p >> 3;
      int c = (p & 7) ^ (r & 7);      // fetch the chunk that lands swizzled
      async_load16(A + (long)(bm + r) * K + k0 + c * 8, As + p * 8);
      async_load16(B + (long)(bn + r) * K + k0 + c * 8, Bs + p * 8);
    }
    __syncthreads();
#pragma unroll
    for (int kk = 0; kk < 2; ++kk) {
      bf16x8 af[4], bfr[4];
#pragma unroll
      for (int i = 0; i < 4; ++i) {
        int row = wm + i * 16 + l15;
        int cc = kk * 4 + quad;
        af[i] = *(const bf16x8*)(As + (row * 8 + (cc ^ (row & 7))) * 8);
      }
#pragma unroll
      for (int j = 0; j < 4; ++j) {
        int row = wn + j * 16 + l15;
        int cc = kk * 4 + quad;
        bfr[j] = *(const bf16x8*)(Bs + (row * 8 + (cc ^ (row & 7))) * 8);
      }
#pragma unroll
      for (int i = 0; i < 4; ++i)
#pragma unroll
        for (int j = 0; j < 4; ++j)
          acc[i][j] = __builtin_amdgcn_mfma_f32_16x16x32_bf16(af[i], bfr[j], acc[i][j], 0, 0, 0);
    }
    __syncthreads();
  }
}

// fused Q,K,V projection: grid dim3(72, 18), x = (sel, N-tile), y = M-tile.
// q,k -> fp32 (RMSNorm wants fp32); v -> bf16 directly (same rounding point
// as the old fp32->vtrans-f2bf path -> bit-identical result).
__global__ __launch_bounds__(256, 2) void gemm_qkv(const u16* __restrict__ A,
                                                   const u16* __restrict__ wq,
                                                   const u16* __restrict__ wk,
                                                   const u16* __restrict__ wv,
                                                   const float* __restrict__ bq,
                                                   const float* __restrict__ bk,
                                                   const float* __restrict__ bv,
                                                   float* __restrict__ qf,
                                                   float* __restrict__ kf,
                                                   u16* __restrict__ vbf) {
  __shared__ u16 As[128 * 64];
  __shared__ u16 Bs[128 * 64];
  const int sel = blockIdx.x / 24;            // 0:q 1:k 2:v
  const int bn = (blockIdx.x % 24) * 128;
  const int bm = blockIdx.y * 128;
  const u16* Bw = (sel == 0) ? wq : (sel == 1) ? wk : wv;
  const float* bias = (sel == 0) ? bq : (sel == 1) ? bk : bv;

  floatx4 acc[4][4];
  gemm_core128(A, Bw, bm, bn, As, Bs, acc);

  const int t = threadIdx.x;
  const int l = t & 63, w = t >> 6;
  const int l15 = l & 15, quad = l >> 4;
  const int wm = (w >> 1) * 64, wn = (w & 1) * 64;

  if (sel < 2) {
    float* C = sel ? kf : qf;
#pragma unroll
    for (int i = 0; i < 4; ++i) {
      const int gm = bm + wm + i * 16 + quad * 4;
#pragma unroll
      for (int j = 0; j < 4; ++j) {
        const int gn = bn + wn + j * 16 + l15;
        const float bb = bias[gn];
#pragma unroll
        for (int r = 0; r < 4; ++r)
          C[(long)(gm + r) * NDIM + gn] = acc[i][j][r] + bb;
      }
    }
  } else {
#pragma unroll
    for (int i = 0; i < 4; ++i) {
      const int gm = bm + wm + i * 16 + quad * 4;
#pragma unroll
      for (int j = 0; j < 4; ++j) {
        const int gn = bn + wn + j * 16 + l15;
        const float bb = bias[gn];
#pragma unroll
        for (int r = 0; r < 4; ++r)
          vbf[(long)(gm + r) * NDIM + gn] = f2bf(acc[i][j][r] + bb);
      }
    }
  }
}

// output projection: grid dim3(24, 18), x = N-tile, y = M-tile.
__global__ __launch_bounds__(256, 2) void gemm_bt(const u16* __restrict__ A,
                                                  const u16* __restrict__ Bw,
                                                  const float* __restrict__ bias,
                                                  float* __restrict__ C) {
  __shared__ u16 As[128 * 64];
  __shared__ u16 Bs[128 * 64];
  const int bm = blockIdx.y * 128;
  const int bn = blockIdx.x * 128;

  floatx4 acc[4][4];
  gemm_core128(A, Bw, bm, bn, As, Bs, acc);

  const int t = threadIdx.x;
  const int l = t & 63, w = t >> 6;
  const int l15 = l & 15, quad = l >> 4;
  const int wm = (w >> 1) * 64, wn = (w & 1) * 64;
#pragma unroll
  for (int i = 0; i < 4; ++i) {
    const int gm = bm + wm + i * 16 + quad * 4;
#pragma unroll
    for (int j = 0; j < 4; ++j) {
      const int gn = bn + wn + j * 16 + l15;
      const float bb = bias[gn];
#pragma unroll
      for (int r = 0; r < 4; ++r)
        C[(long)(gm + r) * NDIM + gn] = acc[i][j][r] + bb;
    }
  }
}

// --------------------------------------------------- fused RMSNorm + 3D RoPE
// blockIdx.y: 0 -> q, 1 -> k
__global__ __launch_bounds__(256) void rmsnorm_rope(const float* __restrict__ qxf,
                                                    const float* __restrict__ kxf,
                                                    const float* __restrict__ gqp,
                                                    const float* __restrict__ gkp,
                                                    const float* __restrict__ freqs,
                                                    const int* __restrict__ gsz,
                                                    u16* __restrict__ qop,
                                                    u16* __restrict__ kop) {
  const int tok = blockIdx.x;
  const int tid = threadIdx.x;
  const float* xf = blockIdx.y ? kxf : qxf;
  const float* g  = blockIdx.y ? gkp : gqp;
  u16* outp       = blockIdx.y ? kop : qop;
  const float* row = xf + (long)tok * NDIM;
  float4 v[3];
  float ss = 0.f;
#pragma unroll
  for (int p = 0; p < 3; ++p) {
    v[p] = ((const float4*)row)[p * 256 + tid];
    ss += v[p].x * v[p].x + v[p].y * v[p].y + v[p].z * v[p].z + v[p].w * v[p].w;
  }
#pragma unroll
  for (int m = 1; m < 64; m <<= 1) ss += __shfl_xor(ss, m);
  __shared__ float red[4];
  if ((tid & 63) == 0) red[tid >> 6] = ss;
  __syncthreads();
  ss = red[0] + red[1] + red[2] + red[3];
  const float scale = rsqrtf(ss * (1.0f / NDIM) + 1e-6f);

  const int gh = gsz[1], gw = gsz[2];
  const int hw = gh * gw;
  const int fi = tok / hw;
  const int hi = (tok % hw) / gw;
  const int wi = tok % gw;
#pragma unroll
  for (int p = 0; p < 3; ++p) {
    const int e0 = (p * 256 + tid) * 4;
    const float4 gg = ((const float4*)g)[p * 256 + tid];
    const int hh = e0 >> 7;
    const int d = e0 & 127;
    const int c0 = d >> 1;
    int pos0 = (c0 < 22) ? fi : ((c0 < 43) ? hi : wi);
    int pos1 = (c0 + 1 < 22) ? fi : ((c0 + 1 < 43) ? hi : wi);
    float th0 = freqs[pos0 * 64 + c0];
    float th1 = freqs[pos1 * 64 + c0 + 1];
    float s0, cc0, s1, cc1;
    __sincosf(th0, &s0, &cc0);
    __sincosf(th1, &s1, &cc1);
    float x0 = v[p].x * scale * gg.x;
    float x1 = v[p].y * scale * gg.y;
    float x2 = v[p].z * scale * gg.z;
    float x3 = v[p].w * scale * gg.w;
    union { u16 h[4]; uint2 u; } o;
    o.h[0] = f2bf(x0 * cc0 - x1 * s0);
    o.h[1] = f2bf(x0 * s0 + x1 * cc0);
    o.h[2] = f2bf(x2 * cc1 - x3 * s1);
    o.h[3] = f2bf(x2 * s1 + x3 * cc1);
    *(uint2*)(outp + ((long)hh * S_LEN + tok) * HD + d) = o.u;
  }
}

// ----------------------------------------------- V: [S,3072] bf16 -> [3072,S] bf16
__global__ __launch_bounds__(256) void vtrans(const u16* __restrict__ vb,
                                              u16* __restrict__ vt) {
  __shared__ u16 tile[64][66];
  const int c0 = blockIdx.x * 64;
  const int t0 = blockIdx.y * 64;
  const int tid = threadIdx.x;
#pragma unroll
  for (int it = 0; it < 16; ++it) {
    int idx = it * 256 + tid;
    int r = idx >> 6, c = idx & 63;
    tile[r][c] = vb[(long)(t0 + r) * NDIM + c0 + c];
  }
  __syncthreads();
#pragma unroll
  for (int it = 0; it < 16; ++it) {
    int idx = it * 256 + tid;
    int r = idx >> 6, c = idx & 63;
    vt[(long)(c0 + r) * S_LEN + t0 + c] = tile[c][r];
  }
}

// ------------------------------------------------------------ flash attention
// qb,kb: bf16 [NH][S][HD]; vt: bf16 [NH*HD][S]; out: bf16 [S][3072].
// 432 blocks x 256 threads (4 waves x 32 q-rows, Q-tile 128). K-tile = 64,
// double-buffered (prefetch issued right after the single per-iter barrier).
// NO online max: post-RMSNorm |s*SC| <= ~11 so exp is fp32-safe un-shifted;
// row-sum l comes from an MFMA with an all-ones B operand. LDS = 80 KB ->
// 2 blocks/CU. XCD swizzle: b&7 -> xcd, 3 heads x 18 qtiles per XCD.
__global__ __launch_bounds__(256, 2) void attn_kern(const u16* __restrict__ qb,
                                                    const u16* __restrict__ kb,
                                                    const u16* __restrict__ vt,
                                                    const int* __restrict__ seq_lens,
                                                    u16* __restrict__ ob) {
  __shared__ u16 Kb[2][64 * 128];   // K tile: 64 tok rows x 16 chunks, swz 15
  __shared__ u16 Vb[2][128 * 64];   // V^T tile: 128 d rows x 8 chunks, swz 7
  __shared__ u16 Ps[128 * 64];      // P tile: 128 q rows x 8 chunks, swz 7
  const int b = blockIdx.x;           // 0..431
  const int xcd = b & 7;
  const int slot = b >> 3;            // 0..53
  const int h = xcd * 3 + slot / 18;  // 3 heads per XCD
  const int qt = slot % 18;
  const int t = threadIdx.x;
  const int l = t & 63, w = t >> 6;
  const int l15 = l & 15, quad = l >> 4;
  const int seqlen = seq_lens[0];
  const float SC2 = 0.12753102543f;   // (1/sqrt(128)) * log2(e), for exp2f

  const u16* kbase = kb + (long)h * S_LEN * HD;
  const u16* vbase = vt + (long)h * HD * S_LEN;

  // Q fragments: A-layout m = lane&15, k = quad*8 + j
  bf16x8 qfrag[2][4];
#pragma unroll
  for (int i = 0; i < 2; ++i) {
    const u16* qrow = qb + ((long)h * S_LEN + qt * 128 + w * 32 + i * 16 + l15) * HD + quad * 8;
#pragma unroll
    for (int kk = 0; kk < 4; ++kk) qfrag[i][kk] = *(const bf16x8*)(qrow + kk * 32);
  }

  bf16x8 ones;
#pragma unroll
  for (int i = 0; i < 8; ++i) ones[i] = (__bf16)1.0f;

  floatx4 oacc[2][8];
  floatx4 lacc[2];
#pragma unroll
  for (int i = 0; i < 2; ++i) {
#pragma unroll
    for (int j = 0; j < 8; ++j) oacc[i][j] = {0.f, 0.f, 0.f, 0.f};
    lacc[i] = {0.f, 0.f, 0.f, 0.f};
  }

  // stage K-tile (64x128) + V-tile (128x64) for tile `kt` into buffer `buf`
  auto stage = [&](int kt, int buf) {
#pragma unroll
    for (int i = 0; i < 4; ++i) {
      int p = i * 256 + t;              // 0..1023
      int rk = p >> 4;                  // K: token row 0..63
      int ck = (p & 15) ^ (rk & 15);
      async_load16(kbase + ((long)(kt * 64 + rk)) * HD + ck * 8, &Kb[buf][p * 8]);
      int dv = p >> 3;                  // V: hd row 0..127
      int cv = (p & 7) ^ (dv & 7);
      async_load16(vbase + (long)dv * S_LEN + kt * 64 + cv * 8, &Vb[buf][p * 8]);
    }
  };

  stage(0, 0);

  for (int kt = 0; kt < S_LEN / 64; ++kt) {
    const int cur = kt & 1;
    __syncthreads();                   // tile kt loads done; prev compute done
    if (kt + 1 < S_LEN / 64) stage(kt + 1, cur ^ 1);

    // S = Q K^T  (128q x 64k)
    floatx4 sacc[2][4];
#pragma unroll
    for (int i = 0; i < 2; ++i)
#pragma unroll
      for (int j = 0; j < 4; ++j) sacc[i][j] = {0.f, 0.f, 0.f, 0.f};
#pragma unroll
    for (int kk = 0; kk < 4; ++kk) {
#pragma unroll
      for (int j = 0; j < 4; ++j) {
        int row = j * 16 + l15;
        int cc = kk * 4 + quad;
        bf16x8 bk = *(const bf16x8*)(&Kb[cur][(row * 16 + (cc ^ (row & 15))) * 8]);
        sacc[0][j] = __builtin_amdgcn_mfma_f32_16x16x32_bf16(qfrag[0][kk], bk, sacc[0][j], 0, 0, 0);
        sacc[1][j] = __builtin_amdgcn_mfma_f32_16x16x32_bf16(qfrag[1][kk], bk, sacc[1][j], 0, 0, 0);
      }
    }

    // unshifted softmax numerator: p = 2^(s*SC2)  (masked cols -> 0)
    const bool tail = (kt * 64 + 64 > seqlen);
#pragma unroll
    for (int i = 0; i < 2; ++i)
#pragma unroll
      for (int j = 0; j < 4; ++j)
#pragma unroll
        for (int r = 0; r < 4; ++r) {
          float sv = sacc[i][j][r] * SC2;
          if (tail) {
            int col = kt * 64 + j * 16 + l15;
            if (col >= seqlen) sv = -1e30f;
          }
          sacc[i][j][r] = exp2f(sv);
        }

    // write P into its own buffer (wave-private rows -> no barrier)
#pragma unroll
    for (int i = 0; i < 2; ++i)
#pragma unroll
      for (int j = 0; j < 4; ++j)
#pragma unroll
        for (int r = 0; r < 4; ++r) {
          int rq = w * 32 + i * 16 + quad * 4 + r;   // 0..127
          int ct = j * 16 + l15;                     // 0..63
          int cc = ct >> 3;
          Ps[(rq * 8 + (cc ^ (rq & 7))) * 8 + (ct & 7)] = f2bf(sacc[i][j][r]);
        }

    // O += P V ; l += P @ ones  (A-frags: own rows of Ps)
#pragma unroll
    for (int kl = 0; kl < 2; ++kl) {
      bf16x8 ap[2];
#pragma unroll
      for (int i = 0; i < 2; ++i) {
        int row = w * 32 + i * 16 + l15;
        int cc = kl * 4 + quad;
        ap[i] = *(const bf16x8*)(&Ps[(row * 8 + (cc ^ (row & 7))) * 8]);
      }
      lacc[0] = __builtin_amdgcn_mfma_f32_16x16x32_bf16(ap[0], ones, lacc[0], 0, 0, 0);
      lacc[1] = __builtin_amdgcn_mfma_f32_16x16x32_bf16(ap[1], ones, lacc[1], 0, 0, 0);
#pragma unroll
      for (int j = 0; j < 8; ++j) {
        int d = j * 16 + l15;
        int ccv = kl * 4 + quad;
        bf16x8 bv = *(const bf16x8*)(&Vb[cur][(d * 8 + (ccv ^ (d & 7))) * 8]);
        oacc[0][j] = __builtin_amdgcn_mfma_f32_16x16x32_bf16(ap[0], bv, oacc[0][j], 0, 0, 0);
        oacc[1][j] = __builtin_amdgcn_mfma_f32_16x16x32_bf16(ap[1], bv, oacc[1][j], 0, 0, 0);
      }
    }
  }

  // epilogue: out[t][h*128+d] = O / l
#pragma unroll
  for (int i = 0; i < 2; ++i) {
    float inv[4];
#pragma unroll
    for (int r = 0; r < 4; ++r) inv[r] = 1.0f / lacc[i][r];
#pragma unroll
    for (int j = 0; j < 8; ++j) {
      int gt = qt * 128 + w * 32 + i * 16 + quad * 4;
      int gc = h * HD + j * 16 + l15;
#pragma unroll
      for (int r = 0; r < 4; ++r)
        ob[(long)(gt + r) * NDIM + gc] = f2bf(oacc[i][j][r] * inv[r]);
    }
  }
}

// ----------------------------------------------------------------------------
extern "C" void kernel_launch(void* const* d_in, const int* in_sizes, int n_in,
                              void* d_out, int out_size, void* d_ws, size_t ws_size,
                              hipStream_t stream) {
  const float* x        = (const float*)d_in[0];
  const int*   seq_lens = (const int*)  d_in[1];
  const int*   gsz      = (const int*)  d_in[2];
  const float* freqs    = (const float*)d_in[3];
  const float* wq       = (const float*)d_in[4];
  const float* bq       = (const float*)d_in[5];
  const float* wk       = (const float*)d_in[6];
  const float* bk       = (const float*)d_in[7];
  const float* wv       = (const float*)d_in[8];
  const float* bv       = (const float*)d_in[9];
  const float* wo       = (const float*)d_in[10];
  const float* bo       = (const float*)d_in[11];
  const float* gq       = (const float*)d_in[12];
  const float* gk       = (const float*)d_in[13];
  float* out = (float*)d_out;

  char* ws = (char*)d_ws;
  const size_t SD2 = (size_t)S_LEN * NDIM * 2;   // bf16 [S,3072]
  const size_t W2  = (size_t)NDIM * NDIM * 2;    // bf16 [3072,3072]
  const size_t SD4 = (size_t)S_LEN * NDIM * 4;   // fp32 [S,3072]
  size_t off = 0;
  u16* xb    = (u16*)(ws + off); off += SD2;
  u16* wqb   = (u16*)(ws + off); off += W2;
  u16* wkb   = (u16*)(ws + off); off += W2;
  u16* wvb   = (u16*)(ws + off); off += W2;
  u16* wob   = (u16*)(ws + off); off += W2;
  float* qf  = (float*)(ws + off); off += SD4;
  float* kf  = (float*)(ws + off); off += SD4;
  u16* vbf   = (u16*)(ws + off); off += SD4;    // fp32-sized slot; holds bf16
  u16* qbuf  = (u16*)(ws + off); off += SD2;
  u16* kbuf  = (u16*)(ws + off); off += SD2;
  u16* vtb   = (u16*)(ws + off); off += SD2;
  u16* attnb = (u16*)(ws + off); off += SD2;

  cvt_all<<<3456 + 4 * 4608, 256, 0, stream>>>(x, wq, wk, wv, wo,
                                               xb, wqb, wkb, wvb, wob);

  gemm_qkv<<<dim3(72, 18), 256, 0, stream>>>(xb, wqb, wkb, wvb,
                                             bq, bk, bv, qf, kf, vbf);

  rmsnorm_rope<<<dim3(S_LEN, 2), 256, 0, stream>>>(qf, kf, gq, gk, freqs, gsz,
                                                   qbuf, kbuf);
  vtrans<<<dim3(NDIM / 64, S_LEN / 64), 256, 0, stream>>>(vbf, vtb);

  attn_kern<<<432, 256, 0, stream>>>(qbuf, kbuf, vtb, seq_lens, attnb);

  gemm_bt<<<dim3(24, 18), 256, 0, stream>>>(attnb, wob, bo, out);
}

// Round 4
// 518.310 us; speedup vs baseline: 1.1438x; 1.0651x over previous
//
#include <hip/hip_runtime.h>
#include <hip/hip_bf16.h>
#include <cstdint>

#define S_LEN 2304
#define NDIM  3072
#define NH    24
#define HD    128

typedef unsigned short u16;
typedef __bf16  bf16x8  __attribute__((ext_vector_type(8)));
typedef float   floatx4 __attribute__((ext_vector_type(4)));

__device__ __forceinline__ u16 f2bf(float x) {
  union { float f; unsigned int u; } a; a.f = x;
  unsigned int r = (a.u + 0x7FFFu + ((a.u >> 16) & 1u)) >> 16;
  return (u16)r;
}

// async 16B global->LDS (direct-to-shared DMA). LDS dest must be
// wave-uniform base + lane*16 -- all call sites arrange that.
__device__ __forceinline__ void async_load16(const void* g, void* l) {
  auto gp = (const __attribute__((address_space(1))) unsigned int*)(unsigned long long)(g);
  auto lp = (__attribute__((address_space(3))) unsigned int*)(unsigned int)(unsigned long long)(l);
  __builtin_amdgcn_global_load_lds(gp, lp, 16, 0, 0);
}

// ------------------------------------------- fp32->bf16, all 5 tensors fused
__global__ __launch_bounds__(256) void cvt_all(const float* __restrict__ x,
                                               const float* __restrict__ w0,
                                               const float* __restrict__ w1,
                                               const float* __restrict__ w2,
                                               const float* __restrict__ w3,
                                               u16* __restrict__ xo,
                                               u16* __restrict__ o0,
                                               u16* __restrict__ o1,
                                               u16* __restrict__ o2,
                                               u16* __restrict__ o3) {
  long b = blockIdx.x;
  const float* in; u16* out;
  if (b < 3456) { in = x; out = xo; }
  else {
    long wi = (b - 3456) / 4608;
    b = (b - 3456) % 4608;
    in  = (wi == 0) ? w0 : (wi == 1) ? w1 : (wi == 2) ? w2 : w3;
    out = (wi == 0) ? o0 : (wi == 1) ? o1 : (wi == 2) ? o2 : o3;
  }
  long i = (b * 256 + threadIdx.x) * 8;
  float4 a = *(const float4*)(in + i);
  float4 c = *(const float4*)(in + i + 4);
  union { u16 h[8]; uint4 u; } r;
  r.h[0] = f2bf(a.x); r.h[1] = f2bf(a.y); r.h[2] = f2bf(a.z); r.h[3] = f2bf(a.w);
  r.h[4] = f2bf(c.x); r.h[5] = f2bf(c.y); r.h[6] = f2bf(c.z); r.h[7] = f2bf(c.w);
  *(uint4*)(out + i) = r.u;
}

// ---------------------------------------------------------------- GEMM core
// C[M,N] = A[M,K] @ B[N,K]^T.  A,B bf16; acc fp32.
// PROVEN structure (887 TF / 145us qkv measured on this problem): 128x128
// tile, BK=64, 256 threads = 4 waves of 64x64, single-buffered LDS (32 KB ->
// ~2 blocks/CU; cross-block wave overlap hides the barrier drain).
// Grid mapping: PLAIN x-fastest over N-tiles (measured optimum; both XCD
// swizzle variants regressed: round-robin 161MB fetch vs chunked 503MB).
__device__ __forceinline__ void gemm_core128(const u16* __restrict__ A,
                                             const u16* __restrict__ B,
                                             int bm, int bn,
                                             u16* As, u16* Bs,
                                             floatx4 acc[4][4]) {
  constexpr int K = NDIM;
  const int t = threadIdx.x;
  const int l = t & 63, w = t >> 6;
  const int l15 = l & 15, quad = l >> 4;
  const int wm = (w >> 1) * 64, wn = (w & 1) * 64;

#pragma unroll
  for (int i = 0; i < 4; ++i)
#pragma unroll
    for (int j = 0; j < 4; ++j) acc[i][j] = {0.f, 0.f, 0.f, 0.f};

  for (int kt = 0; kt < K / 64; ++kt) {
    const int k0 = kt * 64;
#pragma unroll
    for (int i = 0; i < 4; ++i) {
      int p = i * 256 + t;            // chunk index 0..1023 (wave-contiguous)
      int r = p >> 3;
      int c = (p & 7) ^ (r & 7);      // fetch the chunk that lands swizzled
      async_load16(A + (long)(bm + r) * K + k0 + c * 8, As + p * 8);
      async_load16(B + (long)(bn + r) * K + k0 + c * 8, Bs + p * 8);
    }
    __syncthreads();
#pragma unroll
    for (int kk = 0; kk < 2; ++kk) {
      bf16x8 af[4], bfr[4];
#pragma unroll
      for (int i = 0; i < 4; ++i) {
        int row = wm + i * 16 + l15;
        int cc = kk * 4 + quad;
        af[i] = *(const bf16x8*)(As + (row * 8 + (cc ^ (row & 7))) * 8);
      }
#pragma unroll
      for (int j = 0; j < 4; ++j) {
        int row = wn + j * 16 + l15;
        int cc = kk * 4 + quad;
        bfr[j] = *(const bf16x8*)(Bs + (row * 8 + (cc ^ (row & 7))) * 8);
      }
#pragma unroll
      for (int i = 0; i < 4; ++i)
#pragma unroll
        for (int j = 0; j < 4; ++j)
          acc[i][j] = __builtin_amdgcn_mfma_f32_16x16x32_bf16(af[i], bfr[j], acc[i][j], 0, 0, 0);
    }
    __syncthreads();
  }
}

// fused Q,K,V projection: grid dim3(72, 18), x = (sel, N-tile), y = M-tile.
// q,k -> fp32 (RMSNorm wants fp32); v -> bf16 written DIRECTLY TRANSPOSED
// into the attn V^T layout [3072][S] (per lane the 4 acc rows are contiguous
// M -> one 8B store; bit-identical to the old vbf->vtrans path).
__global__ __launch_bounds__(256, 2) void gemm_qkv(const u16* __restrict__ A,
                                                   const u16* __restrict__ wq,
                                                   const u16* __restrict__ wk,
                                                   const u16* __restrict__ wv,
                                                   const float* __restrict__ bq,
                                                   const float* __restrict__ bk,
                                                   const float* __restrict__ bv,
                                                   float* __restrict__ qf,
                                                   float* __restrict__ kf,
                                                   u16* __restrict__ vt) {
  __shared__ u16 As[128 * 64];
  __shared__ u16 Bs[128 * 64];
  const int sel = blockIdx.x / 24;            // 0:q 1:k 2:v
  const int bn = (blockIdx.x % 24) * 128;
  const int bm = blockIdx.y * 128;
  const u16* Bw = (sel == 0) ? wq : (sel == 1) ? wk : wv;
  const float* bias = (sel == 0) ? bq : (sel == 1) ? bk : bv;

  floatx4 acc[4][4];
  gemm_core128(A, Bw, bm, bn, As, Bs, acc);

  const int t = threadIdx.x;
  const int l = t & 63, w = t >> 6;
  const int l15 = l & 15, quad = l >> 4;
  const int wm = (w >> 1) * 64, wn = (w & 1) * 64;

  if (sel < 2) {
    float* C = sel ? kf : qf;
#pragma unroll
    for (int i = 0; i < 4; ++i) {
      const int gm = bm + wm + i * 16 + quad * 4;
#pragma unroll
      for (int j = 0; j < 4; ++j) {
        const int gn = bn + wn + j * 16 + l15;
        const float bb = bias[gn];
#pragma unroll
        for (int r = 0; r < 4; ++r)
          C[(long)(gm + r) * NDIM + gn] = acc[i][j][r] + bb;
      }
    }
  } else {
#pragma unroll
    for (int i = 0; i < 4; ++i) {
      const int gm = bm + wm + i * 16 + quad * 4;   // token index, 4-aligned
#pragma unroll
      for (int j = 0; j < 4; ++j) {
        const int gn = bn + wn + j * 16 + l15;      // v-channel = h*128+d
        const float bb = bias[gn];
        union { u16 h[4]; uint2 u; } o;
#pragma unroll
        for (int r = 0; r < 4; ++r) o.h[r] = f2bf(acc[i][j][r] + bb);
        *(uint2*)(vt + (long)gn * S_LEN + gm) = o.u;
      }
    }
  }
}

// output projection: grid dim3(24, 18), x = N-tile, y = M-tile.
__global__ __launch_bounds__(256, 2) void gemm_bt(const u16* __restrict__ A,
                                                  const u16* __restrict__ Bw,
                                                  const float* __restrict__ bias,
                                                  float* __restrict__ C) {
  __shared__ u16 As[128 * 64];
  __shared__ u16 Bs[128 * 64];
  const int bm = blockIdx.y * 128;
  const int bn = blockIdx.x * 128;

  floatx4 acc[4][4];
  gemm_core128(A, Bw, bm, bn, As, Bs, acc);

  const int t = threadIdx.x;
  const int l = t & 63, w = t >> 6;
  const int l15 = l & 15, quad = l >> 4;
  const int wm = (w >> 1) * 64, wn = (w & 1) * 64;
#pragma unroll
  for (int i = 0; i < 4; ++i) {
    const int gm = bm + wm + i * 16 + quad * 4;
#pragma unroll
    for (int j = 0; j < 4; ++j) {
      const int gn = bn + wn + j * 16 + l15;
      const float bb = bias[gn];
#pragma unroll
      for (int r = 0; r < 4; ++r)
        C[(long)(gm + r) * NDIM + gn] = acc[i][j][r] + bb;
    }
  }
}

// --------------------------------------------------- fused RMSNorm + 3D RoPE
// blockIdx.y: 0 -> q, 1 -> k
__global__ __launch_bounds__(256) void rmsnorm_rope(const float* __restrict__ qxf,
                                                    const float* __restrict__ kxf,
                                                    const float* __restrict__ gqp,
                                                    const float* __restrict__ gkp,
                                                    const float* __restrict__ freqs,
                                                    const int* __restrict__ gsz,
                                                    u16* __restrict__ qop,
                                                    u16* __restrict__ kop) {
  const int tok = blockIdx.x;
  const int tid = threadIdx.x;
  const float* xf = blockIdx.y ? kxf : qxf;
  const float* g  = blockIdx.y ? gkp : gqp;
  u16* outp       = blockIdx.y ? kop : qop;
  const float* row = xf + (long)tok * NDIM;
  float4 v[3];
  float ss = 0.f;
#pragma unroll
  for (int p = 0; p < 3; ++p) {
    v[p] = ((const float4*)row)[p * 256 + tid];
    ss += v[p].x * v[p].x + v[p].y * v[p].y + v[p].z * v[p].z + v[p].w * v[p].w;
  }
#pragma unroll
  for (int m = 1; m < 64; m <<= 1) ss += __shfl_xor(ss, m);
  __shared__ float red[4];
  if ((tid & 63) == 0) red[tid >> 6] = ss;
  __syncthreads();
  ss = red[0] + red[1] + red[2] + red[3];
  const float scale = rsqrtf(ss * (1.0f / NDIM) + 1e-6f);

  const int gh = gsz[1], gw = gsz[2];
  const int hw = gh * gw;
  const int fi = tok / hw;
  const int hi = (tok % hw) / gw;
  const int wi = tok % gw;
#pragma unroll
  for (int p = 0; p < 3; ++p) {
    const int e0 = (p * 256 + tid) * 4;
    const float4 gg = ((const float4*)g)[p * 256 + tid];
    const int hh = e0 >> 7;
    const int d = e0 & 127;
    const int c0 = d >> 1;
    int pos0 = (c0 < 22) ? fi : ((c0 < 43) ? hi : wi);
    int pos1 = (c0 + 1 < 22) ? fi : ((c0 + 1 < 43) ? hi : wi);
    float th0 = freqs[pos0 * 64 + c0];
    float th1 = freqs[pos1 * 64 + c0 + 1];
    float s0, cc0, s1, cc1;
    __sincosf(th0, &s0, &cc0);
    __sincosf(th1, &s1, &cc1);
    float x0 = v[p].x * scale * gg.x;
    float x1 = v[p].y * scale * gg.y;
    float x2 = v[p].z * scale * gg.z;
    float x3 = v[p].w * scale * gg.w;
    union { u16 h[4]; uint2 u; } o;
    o.h[0] = f2bf(x0 * cc0 - x1 * s0);
    o.h[1] = f2bf(x0 * s0 + x1 * cc0);
    o.h[2] = f2bf(x2 * cc1 - x3 * s1);
    o.h[3] = f2bf(x2 * s1 + x3 * cc1);
    *(uint2*)(outp + ((long)hh * S_LEN + tok) * HD + d) = o.u;
  }
}

// ------------------------------------------------------------ flash attention
// qb,kb: bf16 [NH][S][HD]; vt: bf16 [NH*HD][S]; out: bf16 [S][3072].
// 216 blocks x 512 threads (8 waves x 32 q-rows -> Q-tile 256). K-tile = 64,
// double-buffered. Per-wave fragment math identical to the proven 128-row
// version; doubling the Q-tile halves K/V staging + barrier phases per unit
// of MFMA work. NO online max (post-RMSNorm scores are fp32-safe unshifted);
// row-sum l via MFMA with all-ones B. LDS = 32(K)+32(V)+32(P) = 96 KB ->
// 1 block/CU, 8 waves = 2/SIMD (same as the old 2x4-wave config).
// XCD swizzle: b&7 -> xcd, 3 heads x 9 qtiles per XCD (K+V fits 4MB L2).
__global__ __launch_bounds__(512, 2) void attn_kern(const u16* __restrict__ qb,
                                                    const u16* __restrict__ kb,
                                                    const u16* __restrict__ vt,
                                                    const int* __restrict__ seq_lens,
                                                    u16* __restrict__ ob) {
  __shared__ u16 Kb[2][64 * 128];   // K tile: 64 tok rows x 16 chunks, swz 15
  __shared__ u16 Vb[2][128 * 64];   // V^T tile: 128 d rows x 8 chunks, swz 7
  __shared__ u16 Ps[256 * 64];      // P tile: 256 q rows x 8 chunks, swz 7
  const int b = blockIdx.x;           // 0..215
  const int xcd = b & 7;
  const int slot = b >> 3;            // 0..26
  const int h = xcd * 3 + slot / 9;   // 3 heads per XCD
  const int qt = slot % 9;
  const int t = threadIdx.x;
  const int l = t & 63, w = t >> 6;   // 8 waves
  const int l15 = l & 15, quad = l >> 4;
  const int seqlen = seq_lens[0];
  const float SC2 = 0.12753102543f;   // (1/sqrt(128)) * log2(e), for exp2f

  const u16* kbase = kb + (long)h * S_LEN * HD;
  const u16* vbase = vt + (long)h * HD * S_LEN;

  // Q fragments: A-layout m = lane&15, k = quad*8 + j
  bf16x8 qfrag[2][4];
#pragma unroll
  for (int i = 0; i < 2; ++i) {
    const u16* qrow = qb + ((long)h * S_LEN + qt * 256 + w * 32 + i * 16 + l15) * HD + quad * 8;
#pragma unroll
    for (int kk = 0; kk < 4; ++kk) qfrag[i][kk] = *(const bf16x8*)(qrow + kk * 32);
  }

  bf16x8 ones;
#pragma unroll
  for (int i = 0; i < 8; ++i) ones[i] = (__bf16)1.0f;

  floatx4 oacc[2][8];
  floatx4 lacc[2];
#pragma unroll
  for (int i = 0; i < 2; ++i) {
#pragma unroll
    for (int j = 0; j < 8; ++j) oacc[i][j] = {0.f, 0.f, 0.f, 0.f};
    lacc[i] = {0.f, 0.f, 0.f, 0.f};
  }

  // stage K-tile (64x128) + V-tile (128x64) for tile `kt` into buffer `buf`
  auto stage = [&](int kt, int buf) {
#pragma unroll
    for (int i = 0; i < 2; ++i) {
      int p = i * 512 + t;              // 0..1023
      int rk = p >> 4;                  // K: token row 0..63
      int ck = (p & 15) ^ (rk & 15);
      async_load16(kbase + ((long)(kt * 64 + rk)) * HD + ck * 8, &Kb[buf][p * 8]);
      int dv = p >> 3;                  // V: hd row 0..127
      int cv = (p & 7) ^ (dv & 7);
      async_load16(vbase + (long)dv * S_LEN + kt * 64 + cv * 8, &Vb[buf][p * 8]);
    }
  };

  stage(0, 0);

  for (int kt = 0; kt < S_LEN / 64; ++kt) {
    const int cur = kt & 1;
    __syncthreads();                   // tile kt loads done; prev compute done
    if (kt + 1 < S_LEN / 64) stage(kt + 1, cur ^ 1);

    // S = Q K^T  (256q x 64k, 32 rows per wave)
    floatx4 sacc[2][4];
#pragma unroll
    for (int i = 0; i < 2; ++i)
#pragma unroll
      for (int j = 0; j < 4; ++j) sacc[i][j] = {0.f, 0.f, 0.f, 0.f};
    __builtin_amdgcn_s_setprio(1);
#pragma unroll
    for (int kk = 0; kk < 4; ++kk) {
#pragma unroll
      for (int j = 0; j < 4; ++j) {
        int row = j * 16 + l15;
        int cc = kk * 4 + quad;
        bf16x8 bk = *(const bf16x8*)(&Kb[cur][(row * 16 + (cc ^ (row & 15))) * 8]);
        sacc[0][j] = __builtin_amdgcn_mfma_f32_16x16x32_bf16(qfrag[0][kk], bk, sacc[0][j], 0, 0, 0);
        sacc[1][j] = __builtin_amdgcn_mfma_f32_16x16x32_bf16(qfrag[1][kk], bk, sacc[1][j], 0, 0, 0);
      }
    }
    __builtin_amdgcn_s_setprio(0);

    // unshifted softmax numerator: p = 2^(s*SC2)  (masked cols -> 0)
    const bool tail = (kt * 64 + 64 > seqlen);
#pragma unroll
    for (int i = 0; i < 2; ++i)
#pragma unroll
      for (int j = 0; j < 4; ++j)
#pragma unroll
        for (int r = 0; r < 4; ++r) {
          float sv = sacc[i][j][r] * SC2;
          if (tail) {
            int col = kt * 64 + j * 16 + l15;
            if (col >= seqlen) sv = -1e30f;
          }
          sacc[i][j][r] = exp2f(sv);
        }

    // write P into its own buffer (wave-private rows -> no barrier)
#pragma unroll
    for (int i = 0; i < 2; ++i)
#pragma unroll
      for (int j = 0; j < 4; ++j)
#pragma unroll
        for (int r = 0; r < 4; ++r) {
          int rq = w * 32 + i * 16 + quad * 4 + r;   // 0..255
          int ct = j * 16 + l15;                     // 0..63
          int cc = ct >> 3;
          Ps[(rq * 8 + (cc ^ (rq & 7))) * 8 + (ct & 7)] = f2bf(sacc[i][j][r]);
        }

    // O += P V ; l += P @ ones  (A-frags: own rows of Ps)
    __builtin_amdgcn_s_setprio(1);
#pragma unroll
    for (int kl = 0; kl < 2; ++kl) {
      bf16x8 ap[2];
#pragma unroll
      for (int i = 0; i < 2; ++i) {
        int row = w * 32 + i * 16 + l15;
        int cc = kl * 4 + quad;
        ap[i] = *(const bf16x8*)(&Ps[(row * 8 + (cc ^ (row & 7))) * 8]);
      }
      lacc[0] = __builtin_amdgcn_mfma_f32_16x16x32_bf16(ap[0], ones, lacc[0], 0, 0, 0);
      lacc[1] = __builtin_amdgcn_mfma_f32_16x16x32_bf16(ap[1], ones, lacc[1], 0, 0, 0);
#pragma unroll
      for (int j = 0; j < 8; ++j) {
        int d = j * 16 + l15;
        int ccv = kl * 4 + quad;
        bf16x8 bv = *(const bf16x8*)(&Vb[cur][(d * 8 + (ccv ^ (d & 7))) * 8]);
        oacc[0][j] = __builtin_amdgcn_mfma_f32_16x16x32_bf16(ap[0], bv, oacc[0][j], 0, 0, 0);
        oacc[1][j] = __builtin_amdgcn_mfma_f32_16x16x32_bf16(ap[1], bv, oacc[1][j], 0, 0, 0);
      }
    }
    __builtin_amdgcn_s_setprio(0);
  }

  // epilogue: out[t][h*128+d] = O / l
#pragma unroll
  for (int i = 0; i < 2; ++i) {
    float inv[4];
#pragma unroll
    for (int r = 0; r < 4; ++r) inv[r] = 1.0f / lacc[i][r];
#pragma unroll
    for (int j = 0; j < 8; ++j) {
      int gt = qt * 256 + w * 32 + i * 16 + quad * 4;
      int gc = h * HD + j * 16 + l15;
#pragma unroll
      for (int r = 0; r < 4; ++r)
        ob[(long)(gt + r) * NDIM + gc] = f2bf(oacc[i][j][r] * inv[r]);
    }
  }
}

// ----------------------------------------------------------------------------
extern "C" void kernel_launch(void* const* d_in, const int* in_sizes, int n_in,
                              void* d_out, int out_size, void* d_ws, size_t ws_size,
                              hipStream_t stream) {
  const float* x        = (const float*)d_in[0];
  const int*   seq_lens = (const int*)  d_in[1];
  const int*   gsz      = (const int*)  d_in[2];
  const float* freqs    = (const float*)d_in[3];
  const float* wq       = (const float*)d_in[4];
  const float* bq       = (const float*)d_in[5];
  const float* wk       = (const float*)d_in[6];
  const float* bk       = (const float*)d_in[7];
  const float* wv       = (const float*)d_in[8];
  const float* bv       = (const float*)d_in[9];
  const float* wo       = (const float*)d_in[10];
  const float* bo       = (const float*)d_in[11];
  const float* gq       = (const float*)d_in[12];
  const float* gk       = (const float*)d_in[13];
  float* out = (float*)d_out;

  char* ws = (char*)d_ws;
  const size_t SD2 = (size_t)S_LEN * NDIM * 2;   // bf16 [S,3072]
  const size_t W2  = (size_t)NDIM * NDIM * 2;    // bf16 [3072,3072]
  const size_t SD4 = (size_t)S_LEN * NDIM * 4;   // fp32 [S,3072]
  size_t off = 0;
  u16* xb    = (u16*)(ws + off); off += SD2;
  u16* wqb   = (u16*)(ws + off); off += W2;
  u16* wkb   = (u16*)(ws + off); off += W2;
  u16* wvb   = (u16*)(ws + off); off += W2;
  u16* wob   = (u16*)(ws + off); off += W2;
  float* qf  = (float*)(ws + off); off += SD4;
  float* kf  = (float*)(ws + off); off += SD4;
  u16* vtb   = (u16*)(ws + off); off += SD2;     // V^T bf16 [3072,S]
  u16* qbuf  = (u16*)(ws + off); off += SD2;
  u16* kbuf  = (u16*)(ws + off); off += SD2;
  u16* attnb = (u16*)(ws + off); off += SD2;

  cvt_all<<<3456 + 4 * 4608, 256, 0, stream>>>(x, wq, wk, wv, wo,
                                               xb, wqb, wkb, wvb, wob);

  gemm_qkv<<<dim3(72, 18), 256, 0, stream>>>(xb, wqb, wkb, wvb,
                                             bq, bk, bv, qf, kf, vtb);

  rmsnorm_rope<<<dim3(S_LEN, 2), 256, 0, stream>>>(qf, kf, gq, gk, freqs, gsz,
                                                   qbuf, kbuf);

  attn_kern<<<216, 512, 0, stream>>>(qbuf, kbuf, vtb, seq_lens, attnb);

  gemm_bt<<<dim3(24, 18), 256, 0, stream>>>(attnb, wob, bo, out);
}

// Round 5
// 515.077 us; speedup vs baseline: 1.1510x; 1.0063x over previous
//
#include <hip/hip_runtime.h>
#include <hip/hip_bf16.h>
#include <cstdint>

#define S_LEN 2304
#define NDIM  3072
#define NH    24
#define HD    128

typedef unsigned short u16;
typedef __bf16  bf16x8  __attribute__((ext_vector_type(8)));
typedef float   floatx4 __attribute__((ext_vector_type(4)));

// HW bf16 convert (RNE) -- compiler pairs into v_cvt_pk_bf16_f32.
// Bit-identical to the old add-round-shift f2bf for all non-NaN inputs.
__device__ __forceinline__ u16 f2bf(float x) {
  union { __bf16 b; u16 u; } c;
  c.b = (__bf16)x;
  return c.u;
}

// async 16B global->LDS (direct-to-shared DMA). LDS dest must be
// wave-uniform base + lane*16 -- all call sites arrange that.
__device__ __forceinline__ void async_load16(const void* g, void* l) {
  auto gp = (const __attribute__((address_space(1))) unsigned int*)(unsigned long long)(g);
  auto lp = (__attribute__((address_space(3))) unsigned int*)(unsigned int)(unsigned long long)(l);
  __builtin_amdgcn_global_load_lds(gp, lp, 16, 0, 0);
}

// ------------------------------------------- fp32->bf16, all 5 tensors fused
// Lane-unit-stride: per wave both loads are contiguous 1KB bursts (the old
// 8-floats-per-thread layout made lanes stride 32B -> half-used segments).
__global__ __launch_bounds__(256) void cvt_all(const float* __restrict__ x,
                                               const float* __restrict__ w0,
                                               const float* __restrict__ w1,
                                               const float* __restrict__ w2,
                                               const float* __restrict__ w3,
                                               u16* __restrict__ xo,
                                               u16* __restrict__ o0,
                                               u16* __restrict__ o1,
                                               u16* __restrict__ o2,
                                               u16* __restrict__ o3) {
  long b = blockIdx.x;
  const float* in; u16* out;
  if (b < 3456) { in = x; out = xo; }
  else {
    long wi = (b - 3456) / 4608;
    b = (b - 3456) % 4608;
    in  = (wi == 0) ? w0 : (wi == 1) ? w1 : (wi == 2) ? w2 : w3;
    out = (wi == 0) ? o0 : (wi == 1) ? o1 : (wi == 2) ? o2 : o3;
  }
  const long f4 = b * 512 + threadIdx.x;      // float4 index
  const float4* in4 = (const float4*)in;
  float4 a = in4[f4];
  float4 c = in4[f4 + 256];
  union { u16 h[4]; uint2 u; } r0, r1;
  r0.h[0] = f2bf(a.x); r0.h[1] = f2bf(a.y); r0.h[2] = f2bf(a.z); r0.h[3] = f2bf(a.w);
  r1.h[0] = f2bf(c.x); r1.h[1] = f2bf(c.y); r1.h[2] = f2bf(c.z); r1.h[3] = f2bf(c.w);
  *(uint2*)(out + f4 * 4)         = r0.u;
  *(uint2*)(out + (f4 + 256) * 4) = r1.u;
}

// ---------------------------------------------------------------- GEMM core
// C[M,N] = A[M,K] @ B[N,K]^T.  A,B bf16; acc fp32.
// PROVEN structure (887 TF / 145us qkv measured on this problem): 128x128
// tile, BK=64, 256 threads = 4 waves of 64x64, single-buffered LDS (32 KB ->
// ~2 blocks/CU; cross-block wave overlap hides the barrier drain).
// Grid mapping: PLAIN x-fastest over N-tiles (measured optimum; both XCD
// swizzle variants regressed: round-robin 161MB fetch vs chunked 503MB).
__device__ __forceinline__ void gemm_core128(const u16* __restrict__ A,
                                             const u16* __restrict__ B,
                                             int bm, int bn,
                                             u16* As, u16* Bs,
                                             floatx4 acc[4][4]) {
  constexpr int K = NDIM;
  const int t = threadIdx.x;
  const int l = t & 63, w = t >> 6;
  const int l15 = l & 15, quad = l >> 4;
  const int wm = (w >> 1) * 64, wn = (w & 1) * 64;

#pragma unroll
  for (int i = 0; i < 4; ++i)
#pragma unroll
    for (int j = 0; j < 4; ++j) acc[i][j] = {0.f, 0.f, 0.f, 0.f};

  for (int kt = 0; kt < K / 64; ++kt) {
    const int k0 = kt * 64;
#pragma unroll
    for (int i = 0; i < 4; ++i) {
      int p = i * 256 + t;            // chunk index 0..1023 (wave-contiguous)
      int r = p >> 3;
      int c = (p & 7) ^ (r & 7);      // fetch the chunk that lands swizzled
      async_load16(A + (long)(bm + r) * K + k0 + c * 8, As + p * 8);
      async_load16(B + (long)(bn + r) * K + k0 + c * 8, Bs + p * 8);
    }
    __syncthreads();
#pragma unroll
    for (int kk = 0; kk < 2; ++kk) {
      bf16x8 af[4], bfr[4];
#pragma unroll
      for (int i = 0; i < 4; ++i) {
        int row = wm + i * 16 + l15;
        int cc = kk * 4 + quad;
        af[i] = *(const bf16x8*)(As + (row * 8 + (cc ^ (row & 7))) * 8);
      }
#pragma unroll
      for (int j = 0; j < 4; ++j) {
        int row = wn + j * 16 + l15;
        int cc = kk * 4 + quad;
        bfr[j] = *(const bf16x8*)(Bs + (row * 8 + (cc ^ (row & 7))) * 8);
      }
#pragma unroll
      for (int i = 0; i < 4; ++i)
#pragma unroll
        for (int j = 0; j < 4; ++j)
          acc[i][j] = __builtin_amdgcn_mfma_f32_16x16x32_bf16(af[i], bfr[j], acc[i][j], 0, 0, 0);
    }
    __syncthreads();
  }
}

// fused Q,K,V projection: grid dim3(72, 18), x = (sel, N-tile), y = M-tile.
// q,k -> fp32 (RMSNorm wants fp32); v -> bf16 written DIRECTLY TRANSPOSED
// into the attn V^T layout [3072][S] (per lane the 4 acc rows are contiguous
// M -> one 8B store; bit-identical to a separate transpose pass).
__global__ __launch_bounds__(256, 2) void gemm_qkv(const u16* __restrict__ A,
                                                   const u16* __restrict__ wq,
                                                   const u16* __restrict__ wk,
                                                   const u16* __restrict__ wv,
                                                   const float* __restrict__ bq,
                                                   const float* __restrict__ bk,
                                                   const float* __restrict__ bv,
                                                   float* __restrict__ qf,
                                                   float* __restrict__ kf,
                                                   u16* __restrict__ vt) {
  __shared__ u16 As[128 * 64];
  __shared__ u16 Bs[128 * 64];
  const int sel = blockIdx.x / 24;            // 0:q 1:k 2:v
  const int bn = (blockIdx.x % 24) * 128;
  const int bm = blockIdx.y * 128;
  const u16* Bw = (sel == 0) ? wq : (sel == 1) ? wk : wv;
  const float* bias = (sel == 0) ? bq : (sel == 1) ? bk : bv;

  floatx4 acc[4][4];
  gemm_core128(A, Bw, bm, bn, As, Bs, acc);

  const int t = threadIdx.x;
  const int l = t & 63, w = t >> 6;
  const int l15 = l & 15, quad = l >> 4;
  const int wm = (w >> 1) * 64, wn = (w & 1) * 64;

  if (sel < 2) {
    float* C = sel ? kf : qf;
#pragma unroll
    for (int i = 0; i < 4; ++i) {
      const int gm = bm + wm + i * 16 + quad * 4;
#pragma unroll
      for (int j = 0; j < 4; ++j) {
        const int gn = bn + wn + j * 16 + l15;
        const float bb = bias[gn];
#pragma unroll
        for (int r = 0; r < 4; ++r)
          C[(long)(gm + r) * NDIM + gn] = acc[i][j][r] + bb;
      }
    }
  } else {
#pragma unroll
    for (int i = 0; i < 4; ++i) {
      const int gm = bm + wm + i * 16 + quad * 4;   // token index, 4-aligned
#pragma unroll
      for (int j = 0; j < 4; ++j) {
        const int gn = bn + wn + j * 16 + l15;      // v-channel = h*128+d
        const float bb = bias[gn];
        union { u16 h[4]; uint2 u; } o;
#pragma unroll
        for (int r = 0; r < 4; ++r) o.h[r] = f2bf(acc[i][j][r] + bb);
        *(uint2*)(vt + (long)gn * S_LEN + gm) = o.u;
      }
    }
  }
}

// output projection: grid dim3(24, 18), x = N-tile, y = M-tile.
__global__ __launch_bounds__(256, 2) void gemm_bt(const u16* __restrict__ A,
                                                  const u16* __restrict__ Bw,
                                                  const float* __restrict__ bias,
                                                  float* __restrict__ C) {
  __shared__ u16 As[128 * 64];
  __shared__ u16 Bs[128 * 64];
  const int bm = blockIdx.y * 128;
  const int bn = blockIdx.x * 128;

  floatx4 acc[4][4];
  gemm_core128(A, Bw, bm, bn, As, Bs, acc);

  const int t = threadIdx.x;
  const int l = t & 63, w = t >> 6;
  const int l15 = l & 15, quad = l >> 4;
  const int wm = (w >> 1) * 64, wn = (w & 1) * 64;
#pragma unroll
  for (int i = 0; i < 4; ++i) {
    const int gm = bm + wm + i * 16 + quad * 4;
#pragma unroll
    for (int j = 0; j < 4; ++j) {
      const int gn = bn + wn + j * 16 + l15;
      const float bb = bias[gn];
#pragma unroll
      for (int r = 0; r < 4; ++r)
        C[(long)(gm + r) * NDIM + gn] = acc[i][j][r] + bb;
    }
  }
}

// --------------------------------------------------- fused RMSNorm + 3D RoPE
// blockIdx.y: 0 -> q, 1 -> k
__global__ __launch_bounds__(256) void rmsnorm_rope(const float* __restrict__ qxf,
                                                    const float* __restrict__ kxf,
                                                    const float* __restrict__ gqp,
                                                    const float* __restrict__ gkp,
                                                    const float* __restrict__ freqs,
                                                    const int* __restrict__ gsz,
                                                    u16* __restrict__ qop,
                                                    u16* __restrict__ kop) {
  const int tok = blockIdx.x;
  const int tid = threadIdx.x;
  const float* xf = blockIdx.y ? kxf : qxf;
  const float* g  = blockIdx.y ? gkp : gqp;
  u16* outp       = blockIdx.y ? kop : qop;
  const float* row = xf + (long)tok * NDIM;
  float4 v[3];
  float ss = 0.f;
#pragma unroll
  for (int p = 0; p < 3; ++p) {
    v[p] = ((const float4*)row)[p * 256 + tid];
    ss += v[p].x * v[p].x + v[p].y * v[p].y + v[p].z * v[p].z + v[p].w * v[p].w;
  }
#pragma unroll
  for (int m = 1; m < 64; m <<= 1) ss += __shfl_xor(ss, m);
  __shared__ float red[4];
  if ((tid & 63) == 0) red[tid >> 6] = ss;
  __syncthreads();
  ss = red[0] + red[1] + red[2] + red[3];
  const float scale = rsqrtf(ss * (1.0f / NDIM) + 1e-6f);

  const int gh = gsz[1], gw = gsz[2];
  const int hw = gh * gw;
  const int fi = tok / hw;
  const int hi = (tok % hw) / gw;
  const int wi = tok % gw;
#pragma unroll
  for (int p = 0; p < 3; ++p) {
    const int e0 = (p * 256 + tid) * 4;
    const float4 gg = ((const float4*)g)[p * 256 + tid];
    const int hh = e0 >> 7;
    const int d = e0 & 127;
    const int c0 = d >> 1;
    int pos0 = (c0 < 22) ? fi : ((c0 < 43) ? hi : wi);
    int pos1 = (c0 + 1 < 22) ? fi : ((c0 + 1 < 43) ? hi : wi);
    float th0 = freqs[pos0 * 64 + c0];
    float th1 = freqs[pos1 * 64 + c0 + 1];
    float s0, cc0, s1, cc1;
    __sincosf(th0, &s0, &cc0);
    __sincosf(th1, &s1, &cc1);
    float x0 = v[p].x * scale * gg.x;
    float x1 = v[p].y * scale * gg.y;
    float x2 = v[p].z * scale * gg.z;
    float x3 = v[p].w * scale * gg.w;
    union { u16 h[4]; uint2 u; } o;
    o.h[0] = f2bf(x0 * cc0 - x1 * s0);
    o.h[1] = f2bf(x0 * s0 + x1 * cc0);
    o.h[2] = f2bf(x2 * cc1 - x3 * s1);
    o.h[3] = f2bf(x2 * s1 + x3 * cc1);
    *(uint2*)(outp + ((long)hh * S_LEN + tok) * HD + d) = o.u;
  }
}

// ------------------------------------------------------------ flash attention
// qb,kb: bf16 [NH][S][HD]; vt: bf16 [NH*HD][S]; out: bf16 [S][3072].
// 216 blocks x 512 threads (8 waves x 32 q-rows -> Q-tile 256). K-tile = 64,
// double-buffered; loop unrolled x2 so the buffer index is compile-time.
// NO online max (post-RMSNorm scores are fp32-safe unshifted); row-sum l via
// MFMA with all-ones B. LDS = 32(K)+32(V)+32(P) = 96 KB -> 1 block/CU,
// 8 waves = 2/SIMD. XCD swizzle: b&7 -> xcd, 3 heads x 9 qtiles per XCD.
// P-write uses HW cvt_pk bf16 (was the VALU hotspot: 32 manual f2bf/iter).
__global__ __launch_bounds__(512, 2) void attn_kern(const u16* __restrict__ qb,
                                                    const u16* __restrict__ kb,
                                                    const u16* __restrict__ vt,
                                                    const int* __restrict__ seq_lens,
                                                    u16* __restrict__ ob) {
  __shared__ u16 Kb[2][64 * 128];   // K tile: 64 tok rows x 16 chunks, swz 15
  __shared__ u16 Vb[2][128 * 64];   // V^T tile: 128 d rows x 8 chunks, swz 7
  __shared__ u16 Ps[256 * 64];      // P tile: 256 q rows x 8 chunks, swz 7
  const int b = blockIdx.x;           // 0..215
  const int xcd = b & 7;
  const int slot = b >> 3;            // 0..26
  const int h = xcd * 3 + slot / 9;   // 3 heads per XCD
  const int qt = slot % 9;
  const int t = threadIdx.x;
  const int l = t & 63, w = t >> 6;   // 8 waves
  const int l15 = l & 15, quad = l >> 4;
  const int seqlen = seq_lens[0];
  const float SC2 = 0.12753102543f;   // (1/sqrt(128)) * log2(e), for exp2f

  const u16* kbase = kb + (long)h * S_LEN * HD;
  const u16* vbase = vt + (long)h * HD * S_LEN;

  // Q fragments: A-layout m = lane&15, k = quad*8 + j
  bf16x8 qfrag[2][4];
#pragma unroll
  for (int i = 0; i < 2; ++i) {
    const u16* qrow = qb + ((long)h * S_LEN + qt * 256 + w * 32 + i * 16 + l15) * HD + quad * 8;
#pragma unroll
    for (int kk = 0; kk < 4; ++kk) qfrag[i][kk] = *(const bf16x8*)(qrow + kk * 32);
  }

  bf16x8 ones;
#pragma unroll
  for (int i = 0; i < 8; ++i) ones[i] = (__bf16)1.0f;

  floatx4 oacc[2][8];
  floatx4 lacc[2];
#pragma unroll
  for (int i = 0; i < 2; ++i) {
#pragma unroll
    for (int j = 0; j < 8; ++j) oacc[i][j] = {0.f, 0.f, 0.f, 0.f};
    lacc[i] = {0.f, 0.f, 0.f, 0.f};
  }

  // stage K-tile (64x128) + V-tile (128x64) for tile `kt` into buffer `buf`
  auto stage = [&](int kt, int buf) {
#pragma unroll
    for (int i = 0; i < 2; ++i) {
      int p = i * 512 + t;              // 0..1023
      int rk = p >> 4;                  // K: token row 0..63
      int ck = (p & 15) ^ (rk & 15);
      async_load16(kbase + ((long)(kt * 64 + rk)) * HD + ck * 8, &Kb[buf][p * 8]);
      int dv = p >> 3;                  // V: hd row 0..127
      int cv = (p & 7) ^ (dv & 7);
      async_load16(vbase + (long)dv * S_LEN + kt * 64 + cv * 8, &Vb[buf][p * 8]);
    }
  };

  // one K-tile step; cur is a compile-time constant at each call site
  auto step = [&](int kt, int cur) {
    __syncthreads();                   // tile kt loads done; prev compute done
    if (kt + 1 < S_LEN / 64) stage(kt + 1, cur ^ 1);

    // S = Q K^T  (256q x 64k, 32 rows per wave)
    floatx4 sacc[2][4];
#pragma unroll
    for (int i = 0; i < 2; ++i)
#pragma unroll
      for (int j = 0; j < 4; ++j) sacc[i][j] = {0.f, 0.f, 0.f, 0.f};
    __builtin_amdgcn_s_setprio(1);
#pragma unroll
    for (int kk = 0; kk < 4; ++kk) {
#pragma unroll
      for (int j = 0; j < 4; ++j) {
        int row = j * 16 + l15;
        int cc = kk * 4 + quad;
        bf16x8 bk = *(const bf16x8*)(&Kb[cur][(row * 16 + (cc ^ (row & 15))) * 8]);
        sacc[0][j] = __builtin_amdgcn_mfma_f32_16x16x32_bf16(qfrag[0][kk], bk, sacc[0][j], 0, 0, 0);
        sacc[1][j] = __builtin_amdgcn_mfma_f32_16x16x32_bf16(qfrag[1][kk], bk, sacc[1][j], 0, 0, 0);
      }
    }
    __builtin_amdgcn_s_setprio(0);

    // unshifted softmax numerator: p = 2^(s*SC2)  (masked cols -> 0)
    const bool tail = (kt * 64 + 64 > seqlen);
#pragma unroll
    for (int i = 0; i < 2; ++i)
#pragma unroll
      for (int j = 0; j < 4; ++j)
#pragma unroll
        for (int r = 0; r < 4; ++r) {
          float sv = sacc[i][j][r] * SC2;
          if (tail) {
            int col = kt * 64 + j * 16 + l15;
            if (col >= seqlen) sv = -1e30f;
          }
          sacc[i][j][r] = exp2f(sv);
        }

    // write P into its own buffer (wave-private rows -> no barrier);
    // HW bf16 casts -> v_cvt_pk + d16 stores
#pragma unroll
    for (int i = 0; i < 2; ++i)
#pragma unroll
      for (int j = 0; j < 4; ++j)
#pragma unroll
        for (int r = 0; r < 4; ++r) {
          int rq = w * 32 + i * 16 + quad * 4 + r;   // 0..255
          int ct = j * 16 + l15;                     // 0..63
          int cc = ct >> 3;
          Ps[(rq * 8 + (cc ^ (rq & 7))) * 8 + (ct & 7)] = f2bf(sacc[i][j][r]);
        }

    // O += P V ; l += P @ ones  (A-frags: own rows of Ps)
    __builtin_amdgcn_s_setprio(1);
#pragma unroll
    for (int kl = 0; kl < 2; ++kl) {
      bf16x8 ap[2];
#pragma unroll
      for (int i = 0; i < 2; ++i) {
        int row = w * 32 + i * 16 + l15;
        int cc = kl * 4 + quad;
        ap[i] = *(const bf16x8*)(&Ps[(row * 8 + (cc ^ (row & 7))) * 8]);
      }
      lacc[0] = __builtin_amdgcn_mfma_f32_16x16x32_bf16(ap[0], ones, lacc[0], 0, 0, 0);
      lacc[1] = __builtin_amdgcn_mfma_f32_16x16x32_bf16(ap[1], ones, lacc[1], 0, 0, 0);
#pragma unroll
      for (int j = 0; j < 8; ++j) {
        int d = j * 16 + l15;
        int ccv = kl * 4 + quad;
        bf16x8 bv = *(const bf16x8*)(&Vb[cur][(d * 8 + (ccv ^ (d & 7))) * 8]);
        oacc[0][j] = __builtin_amdgcn_mfma_f32_16x16x32_bf16(ap[0], bv, oacc[0][j], 0, 0, 0);
        oacc[1][j] = __builtin_amdgcn_mfma_f32_16x16x32_bf16(ap[1], bv, oacc[1][j], 0, 0, 0);
      }
    }
    __builtin_amdgcn_s_setprio(0);
  };

  stage(0, 0);
  for (int kt = 0; kt < S_LEN / 64; kt += 2) {
    step(kt, 0);
    step(kt + 1, 1);
  }

  // epilogue: out[t][h*128+d] = O / l
#pragma unroll
  for (int i = 0; i < 2; ++i) {
    float inv[4];
#pragma unroll
    for (int r = 0; r < 4; ++r) inv[r] = 1.0f / lacc[i][r];
#pragma unroll
    for (int j = 0; j < 8; ++j) {
      int gt = qt * 256 + w * 32 + i * 16 + quad * 4;
      int gc = h * HD + j * 16 + l15;
#pragma unroll
      for (int r = 0; r < 4; ++r)
        ob[(long)(gt + r) * NDIM + gc] = f2bf(oacc[i][j][r] * inv[r]);
    }
  }
}

// ----------------------------------------------------------------------------
extern "C" void kernel_launch(void* const* d_in, const int* in_sizes, int n_in,
                              void* d_out, int out_size, void* d_ws, size_t ws_size,
                              hipStream_t stream) {
  const float* x        = (const float*)d_in[0];
  const int*   seq_lens = (const int*)  d_in[1];
  const int*   gsz      = (const int*)  d_in[2];
  const float* freqs    = (const float*)d_in[3];
  const float* wq       = (const float*)d_in[4];
  const float* bq       = (const float*)d_in[5];
  const float* wk       = (const float*)d_in[6];
  const float* bk       = (const float*)d_in[7];
  const float* wv       = (const float*)d_in[8];
  const float* bv       = (const float*)d_in[9];
  const float* wo       = (const float*)d_in[10];
  const float* bo       = (const float*)d_in[11];
  const float* gq       = (const float*)d_in[12];
  const float* gk       = (const float*)d_in[13];
  float* out = (float*)d_out;

  char* ws = (char*)d_ws;
  const size_t SD2 = (size_t)S_LEN * NDIM * 2;   // bf16 [S,3072]
  const size_t W2  = (size_t)NDIM * NDIM * 2;    // bf16 [3072,3072]
  const size_t SD4 = (size_t)S_LEN * NDIM * 4;   // fp32 [S,3072]
  size_t off = 0;
  u16* xb    = (u16*)(ws + off); off += SD2;
  u16* wqb   = (u16*)(ws + off); off += W2;
  u16* wkb   = (u16*)(ws + off); off += W2;
  u16* wvb   = (u16*)(ws + off); off += W2;
  u16* wob   = (u16*)(ws + off); off += W2;
  float* qf  = (float*)(ws + off); off += SD4;
  float* kf  = (float*)(ws + off); off += SD4;
  u16* vtb   = (u16*)(ws + off); off += SD2;     // V^T bf16 [3072,S]
  u16* qbuf  = (u16*)(ws + off); off += SD2;
  u16* kbuf  = (u16*)(ws + off); off += SD2;
  u16* attnb = (u16*)(ws + off); off += SD2;

  cvt_all<<<3456 + 4 * 4608, 256, 0, stream>>>(x, wq, wk, wv, wo,
                                               xb, wqb, wkb, wvb, wob);

  gemm_qkv<<<dim3(72, 18), 256, 0, stream>>>(xb, wqb, wkb, wvb,
                                             bq, bk, bv, qf, kf, vtb);

  rmsnorm_rope<<<dim3(S_LEN, 2), 256, 0, stream>>>(qf, kf, gq, gk, freqs, gsz,
                                                   qbuf, kbuf);

  attn_kern<<<216, 512, 0, stream>>>(qbuf, kbuf, vtb, seq_lens, attnb);

  gemm_bt<<<dim3(24, 18), 256, 0, stream>>>(attnb, wob, bo, out);
}